// Round 1
// baseline (259.234 us; speedup 1.0000x reference)
//
#include <hip/hip_runtime.h>
#include <hip/hip_bf16.h>

typedef __bf16 bf16x8 __attribute__((ext_vector_type(8)));
typedef float f32x4 __attribute__((ext_vector_type(4)));
typedef unsigned short ushortx8 __attribute__((ext_vector_type(8)));

typedef __attribute__((address_space(1))) void gv_t;
typedef __attribute__((address_space(3))) void lv_t;

__device__ __forceinline__ unsigned short f2bf(float f) {
    unsigned int u = __float_as_uint(f);
    unsigned int r = (u + 0x7fffu + ((u >> 16) & 1u)) >> 16;
    return (unsigned short)r;
}

// ---------------------------------------------------------------- convert x
__global__ void convert_f32_bf16(const float* __restrict__ in,
                                 unsigned short* __restrict__ out, int n4) {
    int i = blockIdx.x * blockDim.x + threadIdx.x;
    if (i >= n4) return;
    float4 v = reinterpret_cast<const float4*>(in)[i];
    ushort4 o;
    o.x = f2bf(v.x); o.y = f2bf(v.y); o.z = f2bf(v.z); o.w = f2bf(v.w);
    reinterpret_cast<ushort4*>(out)[i] = o;
}

// ------------------------------------------------- transpose + convert W
// in: float [K][N] row-major; out: bf16 [N][K] row-major
__global__ void transpose_convert(const float* __restrict__ in,
                                  unsigned short* __restrict__ out,
                                  int K, int N) {
    __shared__ float t[32][33];
    int n0 = blockIdx.x * 32, k0 = blockIdx.y * 32;
    t[threadIdx.y][threadIdx.x] = in[(size_t)(k0 + threadIdx.y) * N + (n0 + threadIdx.x)];
    __syncthreads();
    out[(size_t)(n0 + threadIdx.y) * K + (k0 + threadIdx.x)] = f2bf(t[threadIdx.x][threadIdx.y]);
}

// ---------------------------------------------------------------- GEMM
// C[M,N] = A[M,K] (bf16 row-major) @ Bt[N,K]^T (bf16 row-major) [+ bias]
// 128x128 tile, BK=32, 256 threads (4 waves, 2x2), 4x4 16x16x32 frags/wave.
template <bool BIAS, bool OUT_BF16>
__global__ __launch_bounds__(256) void gemm_bt(const unsigned short* __restrict__ A,
                                               const unsigned short* __restrict__ Bt,
                                               const float* __restrict__ bias,
                                               void* __restrict__ Cv,
                                               int M, int N, int K) {
    __shared__ alignas(16) unsigned short As[128 * 32];
    __shared__ alignas(16) unsigned short Bs[128 * 32];

    const int t = threadIdx.x;
    const int lane = t & 63;
    const int wid = t >> 6;
    const int wr = wid >> 1, wc = wid & 1;
    const int m0 = blockIdx.y * 128, n0 = blockIdx.x * 128;

    f32x4 acc[4][4] = {};

    for (int k0 = 0; k0 < K; k0 += 32) {
        // ---- stage A,B tiles: 128x32 bf16 each, via global_load_lds x16B
#pragma unroll
        for (int i = 0; i < 2; ++i) {
            int c = i * 256 + t;            // chunk id: 512 chunks of 8 elems
            int row = c >> 2;
            int col = (c & 3) * 8;
            const unsigned short* ga = A + (size_t)(m0 + row) * K + k0 + col;
            const unsigned short* gb = Bt + (size_t)(n0 + row) * K + k0 + col;
            __builtin_amdgcn_global_load_lds((gv_t*)ga, (lv_t*)(As + c * 8), 16, 0, 0);
            __builtin_amdgcn_global_load_lds((gv_t*)gb, (lv_t*)(Bs + c * 8), 16, 0, 0);
        }
        __syncthreads();

        bf16x8 af[4], bfr[4];
#pragma unroll
        for (int i = 0; i < 4; ++i)
            af[i] = *reinterpret_cast<const bf16x8*>(As + (wr * 64 + i * 16 + (lane & 15)) * 32 + (lane >> 4) * 8);
#pragma unroll
        for (int j = 0; j < 4; ++j)
            bfr[j] = *reinterpret_cast<const bf16x8*>(Bs + (wc * 64 + j * 16 + (lane & 15)) * 32 + (lane >> 4) * 8);
#pragma unroll
        for (int i = 0; i < 4; ++i)
#pragma unroll
            for (int j = 0; j < 4; ++j)
                acc[i][j] = __builtin_amdgcn_mfma_f32_16x16x32_bf16(af[i], bfr[j], acc[i][j], 0, 0, 0);
        __syncthreads();
    }

    // ---- epilogue: C/D layout col=lane&15, row=(lane>>4)*4+reg
#pragma unroll
    for (int i = 0; i < 4; ++i) {
        int row = m0 + wr * 64 + i * 16 + (lane >> 4) * 4;
#pragma unroll
        for (int j = 0; j < 4; ++j) {
            int col = n0 + wc * 64 + j * 16 + (lane & 15);
            float bv = 0.0f;
            if (BIAS) bv = bias[col];
#pragma unroll
            for (int r = 0; r < 4; ++r) {
                float v = acc[i][j][r] + bv;
                if constexpr (OUT_BF16)
                    ((unsigned short*)Cv)[(size_t)(row + r) * N + col] = f2bf(v);
                else
                    ((float*)Cv)[(size_t)(row + r) * N + col] = v;
            }
        }
    }
}

// ---------------------------------------------------------- flash attention
// qkv: bf16 [B*S][3072]; q at col h*64, k at 1024+h*64, v at 2048+h*64
// ctx: bf16 [B*S][1024] out. Causal. One block = one (b,h) x 64 q-rows.
__global__ __launch_bounds__(256) void attn_fwd(const unsigned short* __restrict__ qkv,
                                                unsigned short* __restrict__ ctx,
                                                int S) {
    const int Hd = 64, TD = 3072, D = 1024;
    __shared__ alignas(16) unsigned short Qs[64 * 64];
    __shared__ alignas(16) unsigned short Ks[64 * 64];
    __shared__ alignas(16) unsigned short Vt[64 * 64];   // [hd][kv]
    __shared__ alignas(16) unsigned short Ps[4][16 * 64];

    const int t = threadIdx.x, lane = t & 63, w = t >> 6;
    const int qt = blockIdx.x;
    const int bh = blockIdx.y;
    const int b = bh >> 4, h = bh & 15;

    const size_t base = ((size_t)b * S) * TD + (size_t)h * Hd;
    const unsigned short* qp = qkv + base;
    const unsigned short* kp = qkv + base + D;
    const unsigned short* vp = qkv + base + 2 * D;

    // stage Q tile (64x64)
    {
        int row = t >> 2, c0 = (t & 3) * 16;
        const unsigned short* g = qp + (size_t)(qt * 64 + row) * TD + c0;
        *reinterpret_cast<uint4*>(Qs + row * 64 + c0) = *reinterpret_cast<const uint4*>(g);
        *reinterpret_cast<uint4*>(Qs + row * 64 + c0 + 8) = *reinterpret_cast<const uint4*>(g + 8);
    }
    __syncthreads();

    bf16x8 aq[2];
#pragma unroll
    for (int kk = 0; kk < 2; ++kk)
        aq[kk] = *reinterpret_cast<const bf16x8*>(Qs + (w * 16 + (lane & 15)) * 64 + kk * 32 + (lane >> 4) * 8);

    f32x4 acc[4] = {};
    float mrow[4] = {-1e30f, -1e30f, -1e30f, -1e30f};
    float lrow[4] = {0.f, 0.f, 0.f, 0.f};

    for (int j0 = 0; j0 <= qt; ++j0) {
        __syncthreads();   // protect previous iteration's LDS reads
        // stage K tile and V^T tile
        {
            int row = t >> 2, c0 = (t & 3) * 16;
            const unsigned short* gk = kp + (size_t)(j0 * 64 + row) * TD + c0;
            *reinterpret_cast<uint4*>(Ks + row * 64 + c0) = *reinterpret_cast<const uint4*>(gk);
            *reinterpret_cast<uint4*>(Ks + row * 64 + c0 + 8) = *reinterpret_cast<const uint4*>(gk + 8);
            const unsigned short* gv = vp + (size_t)(j0 * 64 + row) * TD + c0;
            ushortx8 v0 = *reinterpret_cast<const ushortx8*>(gv);
            ushortx8 v1 = *reinterpret_cast<const ushortx8*>(gv + 8);
#pragma unroll
            for (int e = 0; e < 8; ++e) Vt[(c0 + e) * 64 + row] = v0[e];
#pragma unroll
            for (int e = 0; e < 8; ++e) Vt[(c0 + 8 + e) * 64 + row] = v1[e];
        }
        __syncthreads();

        // QK^T -> scores (16 q-rows x 64 kv per wave)
        f32x4 sc[4];
#pragma unroll
        for (int jn = 0; jn < 4; ++jn) {
            f32x4 s = {};
#pragma unroll
            for (int kk = 0; kk < 2; ++kk) {
                bf16x8 bk = *reinterpret_cast<const bf16x8*>(Ks + (jn * 16 + (lane & 15)) * 64 + kk * 32 + (lane >> 4) * 8);
                s = __builtin_amdgcn_mfma_f32_16x16x32_bf16(aq[kk], bk, s, 0, 0, 0);
            }
            sc[jn] = s * 0.125f;
        }
        // causal mask (diagonal tile only)
        if (j0 == qt) {
            int qg_base = qt * 64 + w * 16 + (lane >> 4) * 4;
#pragma unroll
            for (int jn = 0; jn < 4; ++jn) {
                int kv = j0 * 64 + jn * 16 + (lane & 15);
#pragma unroll
                for (int r = 0; r < 4; ++r)
                    if (kv > qg_base + r) sc[jn][r] = -1e30f;
            }
        }
        // online softmax: row r lives on 16 lanes sharing (lane>>4)
#pragma unroll
        for (int r = 0; r < 4; ++r) {
            float mt = fmaxf(fmaxf(sc[0][r], sc[1][r]), fmaxf(sc[2][r], sc[3][r]));
            mt = fmaxf(mt, __shfl_xor(mt, 1));
            mt = fmaxf(mt, __shfl_xor(mt, 2));
            mt = fmaxf(mt, __shfl_xor(mt, 4));
            mt = fmaxf(mt, __shfl_xor(mt, 8));
            float mnew = fmaxf(mrow[r], mt);
            float alpha = __expf(mrow[r] - mnew);
            float psum = 0.f;
#pragma unroll
            for (int jn = 0; jn < 4; ++jn) {
                float p = __expf(sc[jn][r] - mnew);
                psum += p;
                sc[jn][r] = p;
            }
            psum += __shfl_xor(psum, 1);
            psum += __shfl_xor(psum, 2);
            psum += __shfl_xor(psum, 4);
            psum += __shfl_xor(psum, 8);
            lrow[r] = lrow[r] * alpha + psum;
            mrow[r] = mnew;
#pragma unroll
            for (int jc = 0; jc < 4; ++jc) acc[jc][r] *= alpha;
        }
        // write P (bf16) to per-wave LDS buffer
#pragma unroll
        for (int jn = 0; jn < 4; ++jn)
#pragma unroll
            for (int r = 0; r < 4; ++r)
                Ps[w][((lane >> 4) * 4 + r) * 64 + jn * 16 + (lane & 15)] = f2bf(sc[jn][r]);
        __syncthreads();   // make P visible (and order vs Vt reads)

        // PV: ctx += P @ V
#pragma unroll
        for (int kk = 0; kk < 2; ++kk) {
            bf16x8 ap = *reinterpret_cast<const bf16x8*>(Ps[w] + (lane & 15) * 64 + kk * 32 + (lane >> 4) * 8);
#pragma unroll
            for (int jc = 0; jc < 4; ++jc) {
                bf16x8 bv = *reinterpret_cast<const bf16x8*>(Vt + (jc * 16 + (lane & 15)) * 64 + kk * 32 + (lane >> 4) * 8);
                acc[jc] = __builtin_amdgcn_mfma_f32_16x16x32_bf16(ap, bv, acc[jc], 0, 0, 0);
            }
        }
    }

    // epilogue: ctx = acc / l
#pragma unroll
    for (int jc = 0; jc < 4; ++jc) {
#pragma unroll
        for (int r = 0; r < 4; ++r) {
            int qlocal = w * 16 + (lane >> 4) * 4 + r;
            int s = qt * 64 + qlocal;
            int col = jc * 16 + (lane & 15);
            float v = acc[jc][r] / lrow[r];
            ctx[((size_t)b * S + s) * D + h * Hd + col] = f2bf(v);
        }
    }
}

// ---------------------------------------------------------------- launch
extern "C" void kernel_launch(void* const* d_in, const int* in_sizes, int n_in,
                              void* d_out, int out_size, void* d_ws, size_t ws_size,
                              hipStream_t stream) {
    const float* x = (const float*)d_in[0];
    const float* Wqkv = (const float*)d_in[1];
    const float* bqkv = (const float*)d_in[2];
    const float* Wout = (const float*)d_in[3];
    float* out = (float*)d_out;

    const int B = 2, S = 2048, D = 1024, TD = 3072;
    const int M = B * S;  // 4096

    char* ws = (char*)d_ws;
    unsigned short* x_bf  = (unsigned short*)(ws);               // 8 MiB
    unsigned short* wqkvT = (unsigned short*)(ws + 8388608);     // 6 MiB  [3072][1024]
    unsigned short* woutT = (unsigned short*)(ws + 14680064);    // 2 MiB  [1024][1024]
    unsigned short* qkv   = (unsigned short*)(ws + 16777216);    // 24 MiB [4096][3072]
    unsigned short* ctx   = (unsigned short*)(ws + 41943040);    // 8 MiB  [4096][1024]

    convert_f32_bf16<<<dim3((M * D / 4 + 255) / 256), dim3(256), 0, stream>>>(x, x_bf, M * D / 4);
    transpose_convert<<<dim3(TD / 32, D / 32), dim3(32, 32), 0, stream>>>(Wqkv, wqkvT, D, TD);
    transpose_convert<<<dim3(D / 32, D / 32), dim3(32, 32), 0, stream>>>(Wout, woutT, D, D);

    gemm_bt<true, true><<<dim3(TD / 128, M / 128), dim3(256), 0, stream>>>(
        x_bf, wqkvT, bqkv, (void*)qkv, M, TD, D);

    attn_fwd<<<dim3(S / 64, B * 16), dim3(256), 0, stream>>>(qkv, ctx, S);

    gemm_bt<false, false><<<dim3(D / 128, M / 128), dim3(256), 0, stream>>>(
        ctx, woutT, nullptr, (void*)out, M, D, D);
}

// Round 2
// 148.700 us; speedup vs baseline: 1.7433x; 1.7433x over previous
//
#include <hip/hip_runtime.h>
#include <hip/hip_bf16.h>

typedef __bf16 bf16x8 __attribute__((ext_vector_type(8)));
typedef float f32x4 __attribute__((ext_vector_type(4)));

typedef __attribute__((address_space(1))) void gv_t;
typedef __attribute__((address_space(3))) void lv_t;

__device__ __forceinline__ unsigned short f2bf(float f) {
    unsigned int u = __float_as_uint(f);
    unsigned int r = (u + 0x7fffu + ((u >> 16) & 1u)) >> 16;
    return (unsigned short)r;
}

// ---------------------------------------------------------------- convert x
__global__ void convert_f32_bf16(const float* __restrict__ in,
                                 unsigned short* __restrict__ out, int n4) {
    int i = blockIdx.x * blockDim.x + threadIdx.x;
    if (i >= n4) return;
    float4 v = reinterpret_cast<const float4*>(in)[i];
    ushort4 o;
    o.x = f2bf(v.x); o.y = f2bf(v.y); o.z = f2bf(v.z); o.w = f2bf(v.w);
    reinterpret_cast<ushort4*>(out)[i] = o;
}

// ------------------------------------------------- transpose + convert W
__global__ void transpose_convert(const float* __restrict__ in,
                                  unsigned short* __restrict__ out,
                                  int K, int N) {
    __shared__ float t[32][33];
    int n0 = blockIdx.x * 32, k0 = blockIdx.y * 32;
    t[threadIdx.y][threadIdx.x] = in[(size_t)(k0 + threadIdx.y) * N + (n0 + threadIdx.x)];
    __syncthreads();
    out[(size_t)(n0 + threadIdx.y) * K + (k0 + threadIdx.x)] = f2bf(t[threadIdx.x][threadIdx.y]);
}

// ---------------------------------------------------------------- GEMM
// C[M,N] = A[M,K] bf16 @ Bt[N,K]^T bf16 [+ bias] [cols<1024 scaled 0.125]
template <bool BIAS, bool OUT_BF16, bool QSCALE>
__global__ __launch_bounds__(256) void gemm_bt(const unsigned short* __restrict__ A,
                                               const unsigned short* __restrict__ Bt,
                                               const float* __restrict__ bias,
                                               void* __restrict__ Cv,
                                               int M, int N, int K) {
    __shared__ alignas(16) unsigned short As[128 * 32];
    __shared__ alignas(16) unsigned short Bs[128 * 32];

    const int t = threadIdx.x;
    const int lane = t & 63;
    const int wid = t >> 6;
    const int wr = wid >> 1, wc = wid & 1;
    const int m0 = blockIdx.y * 128, n0 = blockIdx.x * 128;

    f32x4 acc[4][4] = {};

    for (int k0 = 0; k0 < K; k0 += 32) {
#pragma unroll
        for (int i = 0; i < 2; ++i) {
            int c = i * 256 + t;
            int row = c >> 2;
            int col = (c & 3) * 8;
            const unsigned short* ga = A + (size_t)(m0 + row) * K + k0 + col;
            const unsigned short* gb = Bt + (size_t)(n0 + row) * K + k0 + col;
            __builtin_amdgcn_global_load_lds((gv_t*)ga, (lv_t*)(As + c * 8), 16, 0, 0);
            __builtin_amdgcn_global_load_lds((gv_t*)gb, (lv_t*)(Bs + c * 8), 16, 0, 0);
        }
        __syncthreads();

        bf16x8 af[4], bfr[4];
#pragma unroll
        for (int i = 0; i < 4; ++i)
            af[i] = *reinterpret_cast<const bf16x8*>(As + (wr * 64 + i * 16 + (lane & 15)) * 32 + (lane >> 4) * 8);
#pragma unroll
        for (int j = 0; j < 4; ++j)
            bfr[j] = *reinterpret_cast<const bf16x8*>(Bs + (wc * 64 + j * 16 + (lane & 15)) * 32 + (lane >> 4) * 8);
#pragma unroll
        for (int i = 0; i < 4; ++i)
#pragma unroll
            for (int j = 0; j < 4; ++j)
                acc[i][j] = __builtin_amdgcn_mfma_f32_16x16x32_bf16(af[i], bfr[j], acc[i][j], 0, 0, 0);
        __syncthreads();
    }

#pragma unroll
    for (int i = 0; i < 4; ++i) {
        int row = m0 + wr * 64 + i * 16 + (lane >> 4) * 4;
#pragma unroll
        for (int j = 0; j < 4; ++j) {
            int col = n0 + wc * 64 + j * 16 + (lane & 15);
            float bv = 0.0f;
            if (BIAS) bv = bias[col];
#pragma unroll
            for (int r = 0; r < 4; ++r) {
                float v = acc[i][j][r] + bv;
                if constexpr (QSCALE) { if (col < 1024) v *= 0.125f; }
                if constexpr (OUT_BF16)
                    ((unsigned short*)Cv)[(size_t)(row + r) * N + col] = f2bf(v);
                else
                    ((float*)Cv)[(size_t)(row + r) * N + col] = v;
            }
        }
    }
}

// ---------------------------------------------------------- flash attention
// Swapped-operand flash attn. Block = (b,h) x paired q-tiles {pid, 31-pid}.
// 4 waves; wave w owns q-rows w*16..w*16+15 of each 64-row q-tile.
// Lane owns q = w*16 + (lane&15): softmax m/l are lane-scalar.
__global__ __launch_bounds__(256) void attn_fwd(const unsigned short* __restrict__ qkv,
                                                unsigned short* __restrict__ ctx,
                                                int S) {
    const int TD = 3072, D = 1024;
    __shared__ alignas(16) unsigned short Ks[64 * 64];   // [kv][hd], granule-swizzled
    __shared__ alignas(16) unsigned short Vt[64 * 64];   // [hd][kv], granule-swizzled
    __shared__ alignas(16) unsigned short Ps[4][16 * 64];// per-wave [q][kv], swizzled

    const int t = threadIdx.x, lane = t & 63, w = t >> 6;
    const int l15 = lane & 15, l4 = lane >> 4;
    const int pid = blockIdx.x;              // 0..15
    const int bh = blockIdx.y;
    const int b = bh >> 4, h = bh & 15;
    const int QT_lo = pid, QT_hi = 31 - pid;

    const size_t base = ((size_t)b * S) * TD + (size_t)h * 64;
    const unsigned short* qp = qkv + base;
    const unsigned short* kp = qkv + base + D;
    const unsigned short* vp = qkv + base + 2 * D;

    // Q fragments straight from global (B-operand layout: n=q=lane&15)
    bf16x8 aq_hi[2], aq_lo[2];
    {
        const unsigned short* gh = qp + (size_t)(QT_hi * 64 + w * 16 + l15) * TD + l4 * 8;
        aq_hi[0] = *reinterpret_cast<const bf16x8*>(gh);
        aq_hi[1] = *reinterpret_cast<const bf16x8*>(gh + 32);
        const unsigned short* gl = qp + (size_t)(QT_lo * 64 + w * 16 + l15) * TD + l4 * 8;
        aq_lo[0] = *reinterpret_cast<const bf16x8*>(gl);
        aq_lo[1] = *reinterpret_cast<const bf16x8*>(gl + 32);
    }

    f32x4 oc_hi[4] = {}, oc_lo[4] = {};      // O^T frags: row=hd, col=q
    float m_hi = -1e30f, l_hi = 0.f, m_lo = -1e30f, l_lo = 0.f;

    const float L2E = 1.44269504f;

    auto compute = [&](const bf16x8* aq, f32x4* oc, float& mR, float& lR, bool diag) {
        // ---- S^T = mfma(K, Q): lane holds kv = jn*16 + l4*4 + r for q = w*16+l15
        f32x4 sc[4];
#pragma unroll
        for (int jn = 0; jn < 4; ++jn) {
            f32x4 s = {};
#pragma unroll
            for (int kk = 0; kk < 2; ++kk) {
                int row = jn * 16 + l15;
                int g = (kk * 4 + l4) ^ (l15 & 7);
                bf16x8 ak = *reinterpret_cast<const bf16x8*>(Ks + row * 64 + g * 8);
                s = __builtin_amdgcn_mfma_f32_16x16x32_bf16(ak, aq[kk], s, 0, 0, 0);
            }
            sc[jn] = s;
        }
        if (diag) {
            int ql = w * 16 + l15;
#pragma unroll
            for (int jn = 0; jn < 4; ++jn)
#pragma unroll
                for (int r = 0; r < 4; ++r)
                    if (jn * 16 + l4 * 4 + r > ql) sc[jn][r] = -1e30f;
        }
        // ---- online softmax (lane-local row)
        float pm = -1e30f;
#pragma unroll
        for (int jn = 0; jn < 4; ++jn) {
            float a = fmaxf(sc[jn][0], sc[jn][1]);
            float c = fmaxf(sc[jn][2], sc[jn][3]);
            pm = fmaxf(pm, fmaxf(a, c));
        }
        pm = fmaxf(pm, __shfl_xor(pm, 16));
        pm = fmaxf(pm, __shfl_xor(pm, 32));
        float mnew = fmaxf(mR, pm);
        float alpha = exp2f((mR - mnew) * L2E);
        float mn2 = mnew * L2E;
        float ps = 0.f;
#pragma unroll
        for (int jn = 0; jn < 4; ++jn) {
            float p0 = exp2f(sc[jn][0] * L2E - mn2);
            float p1 = exp2f(sc[jn][1] * L2E - mn2);
            float p2 = exp2f(sc[jn][2] * L2E - mn2);
            float p3 = exp2f(sc[jn][3] * L2E - mn2);
            sc[jn][0] = p0; sc[jn][1] = p1; sc[jn][2] = p2; sc[jn][3] = p3;
            ps += (p0 + p1) + (p2 + p3);
        }
        ps += __shfl_xor(ps, 16);
        ps += __shfl_xor(ps, 32);
        lR = lR * alpha + ps;
        mR = mnew;
#pragma unroll
        for (int jc = 0; jc < 4; ++jc) oc[jc] *= alpha;
        // ---- P^T -> Ps[w] (paired bf16 writes, granule-swizzled by q)
        int q = l15;
#pragma unroll
        for (int jn = 0; jn < 4; ++jn)
#pragma unroll
            for (int p = 0; p < 2; ++p) {
                int kv = jn * 16 + l4 * 4 + 2 * p;
                int col = (kv & 7) | ((((kv >> 3) ^ (q & 7)) & 7) << 3);
                unsigned int pk = (unsigned int)f2bf(sc[jn][2 * p]) |
                                  ((unsigned int)f2bf(sc[jn][2 * p + 1]) << 16);
                *reinterpret_cast<unsigned int*>(Ps[w] + q * 64 + col) = pk;
            }
        // ---- O^T += mfma(V^T, P)
#pragma unroll
        for (int kk = 0; kk < 2; ++kk) {
            int gq = (kk * 4 + l4) ^ (q & 7);
            bf16x8 bp = *reinterpret_cast<const bf16x8*>(Ps[w] + q * 64 + gq * 8);
#pragma unroll
            for (int jc = 0; jc < 4; ++jc) {
                int hdrow = jc * 16 + l15;
                int gv = (kk * 4 + l4) ^ (l15 & 7);
                bf16x8 av = *reinterpret_cast<const bf16x8*>(Vt + hdrow * 64 + gv * 8);
                oc[jc] = __builtin_amdgcn_mfma_f32_16x16x32_bf16(av, bp, oc[jc], 0, 0, 0);
            }
        }
    };

    for (int j0 = 0; j0 <= QT_hi; ++j0) {
        if (j0) __syncthreads();     // prev-iter LDS reads done before overwrite
        // ---- stage K (global_load_lds, pre-swizzled source)
#pragma unroll
        for (int rnd = 0; rnd < 2; ++rnd) {
            int c = rnd * 256 + t;
            int row = c >> 3, hh = c & 7;
            const unsigned short* src = kp + (size_t)(j0 * 64 + row) * TD + ((hh ^ (row & 7)) * 8);
            __builtin_amdgcn_global_load_lds((gv_t*)src, (lv_t*)(Ks + c * 8), 16, 0, 0);
        }
        // ---- stage V transposed: coalesced ushort2 loads -> swizzled b128 writes
        {
            int hd = (t & 31) * 2, kvb = (t >> 5) * 8;
            const unsigned short* vsrc = vp + (size_t)(j0 * 64 + kvb) * TD + hd;
            unsigned int vv[8];
#pragma unroll
            for (int e = 0; e < 8; ++e)
                vv[e] = *reinterpret_cast<const unsigned int*>(vsrc + (size_t)e * TD);
            unsigned int r0[4], r1[4];
#pragma unroll
            for (int i = 0; i < 4; ++i) {
                r0[i] = __builtin_amdgcn_perm(vv[2 * i + 1], vv[2 * i], 0x05040100u);
                r1[i] = __builtin_amdgcn_perm(vv[2 * i + 1], vv[2 * i], 0x07060302u);
            }
            int g0 = (kvb >> 3) ^ (hd & 7);
            int g1 = (kvb >> 3) ^ ((hd + 1) & 7);
            *reinterpret_cast<uint4*>(Vt + hd * 64 + g0 * 8) = make_uint4(r0[0], r0[1], r0[2], r0[3]);
            *reinterpret_cast<uint4*>(Vt + (hd + 1) * 64 + g1 * 8) = make_uint4(r1[0], r1[1], r1[2], r1[3]);
        }
        __syncthreads();

        compute(aq_hi, oc_hi, m_hi, l_hi, j0 == QT_hi);
        if (j0 <= QT_lo) compute(aq_lo, oc_lo, m_lo, l_lo, j0 == QT_lo);
    }

    // ---- epilogue: ctx[q][hd] = O^T / l  (paired bf16 stores)
    auto epi = [&](f32x4* oc, float lR, int QT) {
        float inv = 1.0f / lR;
        size_t qg = (size_t)QT * 64 + w * 16 + l15;
        unsigned short* crow = ctx + ((size_t)b * S + qg) * D + h * 64;
#pragma unroll
        for (int jc = 0; jc < 4; ++jc)
#pragma unroll
            for (int p = 0; p < 2; ++p) {
                int hd = jc * 16 + l4 * 4 + 2 * p;
                unsigned int pk = (unsigned int)f2bf(oc[jc][2 * p] * inv) |
                                  ((unsigned int)f2bf(oc[jc][2 * p + 1] * inv) << 16);
                *reinterpret_cast<unsigned int*>(crow + hd) = pk;
            }
    };
    epi(oc_hi, l_hi, QT_hi);
    epi(oc_lo, l_lo, QT_lo);
}

// ---------------------------------------------------------------- launch
extern "C" void kernel_launch(void* const* d_in, const int* in_sizes, int n_in,
                              void* d_out, int out_size, void* d_ws, size_t ws_size,
                              hipStream_t stream) {
    const float* x = (const float*)d_in[0];
    const float* Wqkv = (const float*)d_in[1];
    const float* bqkv = (const float*)d_in[2];
    const float* Wout = (const float*)d_in[3];
    float* out = (float*)d_out;

    const int B = 2, S = 2048, D = 1024, TD = 3072;
    const int M = B * S;  // 4096

    char* ws = (char*)d_ws;
    unsigned short* x_bf  = (unsigned short*)(ws);               // 8 MiB
    unsigned short* wqkvT = (unsigned short*)(ws + 8388608);     // 6 MiB  [3072][1024]
    unsigned short* woutT = (unsigned short*)(ws + 14680064);    // 2 MiB  [1024][1024]
    unsigned short* qkv   = (unsigned short*)(ws + 16777216);    // 24 MiB [4096][3072]
    unsigned short* ctx   = (unsigned short*)(ws + 41943040);    // 8 MiB  [4096][1024]

    convert_f32_bf16<<<dim3((M * D / 4 + 255) / 256), dim3(256), 0, stream>>>(x, x_bf, M * D / 4);
    transpose_convert<<<dim3(TD / 32, D / 32), dim3(32, 32), 0, stream>>>(Wqkv, wqkvT, D, TD);
    transpose_convert<<<dim3(D / 32, D / 32), dim3(32, 32), 0, stream>>>(Wout, woutT, D, D);

    gemm_bt<true, true, true><<<dim3(TD / 128, M / 128), dim3(256), 0, stream>>>(
        x_bf, wqkvT, bqkv, (void*)qkv, M, TD, D);

    attn_fwd<<<dim3(16, 32), dim3(256), 0, stream>>>(qkv, ctx, S);

    gemm_bt<false, false, false><<<dim3(D / 128, M / 128), dim3(256), 0, stream>>>(
        ctx, woutT, nullptr, (void*)out, M, D, D);
}

// Round 3
// 143.765 us; speedup vs baseline: 1.8032x; 1.0343x over previous
//
#include <hip/hip_runtime.h>
#include <hip/hip_bf16.h>

typedef __bf16 bf16x8 __attribute__((ext_vector_type(8)));
typedef float f32x4 __attribute__((ext_vector_type(4)));

typedef __attribute__((address_space(1))) void gv_t;
typedef __attribute__((address_space(3))) void lv_t;

__device__ __forceinline__ unsigned short f2bf(float f) {
    unsigned int u = __float_as_uint(f);
    unsigned int r = (u + 0x7fffu + ((u >> 16) & 1u)) >> 16;
    return (unsigned short)r;
}

__device__ __forceinline__ unsigned int cvt_pk_bf16(float a, float b) {
    unsigned int r;
    asm("v_cvt_pk_bf16_f32 %0, %1, %2" : "=v"(r) : "v"(a), "v"(b));
    return r;
}

// ---------------------------------------------------------------- convert x
__global__ void convert_f32_bf16(const float* __restrict__ in,
                                 unsigned short* __restrict__ out, int n4) {
    int i = blockIdx.x * blockDim.x + threadIdx.x;
    if (i >= n4) return;
    float4 v = reinterpret_cast<const float4*>(in)[i];
    ushort4 o;
    o.x = f2bf(v.x); o.y = f2bf(v.y); o.z = f2bf(v.z); o.w = f2bf(v.w);
    reinterpret_cast<ushort4*>(out)[i] = o;
}

// ------------------------------------------------- transpose + convert W
__global__ void transpose_convert(const float* __restrict__ in,
                                  unsigned short* __restrict__ out,
                                  int K, int N) {
    __shared__ float t[32][33];
    int n0 = blockIdx.x * 32, k0 = blockIdx.y * 32;
    t[threadIdx.y][threadIdx.x] = in[(size_t)(k0 + threadIdx.y) * N + (n0 + threadIdx.x)];
    __syncthreads();
    out[(size_t)(n0 + threadIdx.y) * K + (k0 + threadIdx.x)] = f2bf(t[threadIdx.x][threadIdx.y]);
}

// ---------------------------------------------------------------- GEMM
// C[M,N] = A[M,K] bf16 @ Bt[N,K]^T bf16 [+ bias] [cols<1024 scaled 0.125]
template <bool BIAS, bool OUT_BF16, bool QSCALE>
__global__ __launch_bounds__(256) void gemm_bt(const unsigned short* __restrict__ A,
                                               const unsigned short* __restrict__ Bt,
                                               const float* __restrict__ bias,
                                               void* __restrict__ Cv,
                                               int M, int N, int K) {
    __shared__ alignas(16) unsigned short As[128 * 32];
    __shared__ alignas(16) unsigned short Bs[128 * 32];

    const int t = threadIdx.x;
    const int lane = t & 63;
    const int wid = t >> 6;
    const int wr = wid >> 1, wc = wid & 1;
    const int m0 = blockIdx.y * 128, n0 = blockIdx.x * 128;

    f32x4 acc[4][4] = {};

    for (int k0 = 0; k0 < K; k0 += 32) {
#pragma unroll
        for (int i = 0; i < 2; ++i) {
            int c = i * 256 + t;
            int row = c >> 2;
            int col = (c & 3) * 8;
            const unsigned short* ga = A + (size_t)(m0 + row) * K + k0 + col;
            const unsigned short* gb = Bt + (size_t)(n0 + row) * K + k0 + col;
            __builtin_amdgcn_global_load_lds((gv_t*)ga, (lv_t*)(As + c * 8), 16, 0, 0);
            __builtin_amdgcn_global_load_lds((gv_t*)gb, (lv_t*)(Bs + c * 8), 16, 0, 0);
        }
        __syncthreads();

        bf16x8 af[4], bfr[4];
#pragma unroll
        for (int i = 0; i < 4; ++i)
            af[i] = *reinterpret_cast<const bf16x8*>(As + (wr * 64 + i * 16 + (lane & 15)) * 32 + (lane >> 4) * 8);
#pragma unroll
        for (int j = 0; j < 4; ++j)
            bfr[j] = *reinterpret_cast<const bf16x8*>(Bs + (wc * 64 + j * 16 + (lane & 15)) * 32 + (lane >> 4) * 8);
#pragma unroll
        for (int i = 0; i < 4; ++i)
#pragma unroll
            for (int j = 0; j < 4; ++j)
                acc[i][j] = __builtin_amdgcn_mfma_f32_16x16x32_bf16(af[i], bfr[j], acc[i][j], 0, 0, 0);
        __syncthreads();
    }

#pragma unroll
    for (int i = 0; i < 4; ++i) {
        int row = m0 + wr * 64 + i * 16 + (lane >> 4) * 4;
#pragma unroll
        for (int j = 0; j < 4; ++j) {
            int col = n0 + wc * 64 + j * 16 + (lane & 15);
            float bv = 0.0f;
            if (BIAS) bv = bias[col];
#pragma unroll
            for (int r = 0; r < 4; ++r) {
                float v = acc[i][j][r] + bv;
                if constexpr (QSCALE) { if (col < 1024) v *= 0.125f; }
                if constexpr (OUT_BF16)
                    ((unsigned short*)Cv)[(size_t)(row + r) * N + col] = f2bf(v);
                else
                    ((float*)Cv)[(size_t)(row + r) * N + col] = v;
            }
        }
    }
}

// ---------------------------------------------------------- flash attention
// Swapped-operand flash attn, double-buffered K/V, async stage split.
// Block = (b,h) x paired q-tiles {pid, 31-pid}. 4 waves, wave owns 16 q-rows
// of each tile; lane owns q = w*16 + (lane&15): softmax m/l lane-scalar.
__global__ __launch_bounds__(256) void attn_fwd(const unsigned short* __restrict__ qkv,
                                                unsigned short* __restrict__ ctx,
                                                int S) {
    const int TD = 3072, D = 1024;
    __shared__ alignas(16) unsigned short Ks[2][64 * 64];   // [kv][hd], swizzled
    __shared__ alignas(16) unsigned short Vt[2][64 * 64];   // [hd][kv], swizzled
    __shared__ alignas(16) unsigned short Ps[4][16 * 64];   // per-wave [q][kv], swizzled

    const int t = threadIdx.x, lane = t & 63, w = t >> 6;
    const int l15 = lane & 15, l4 = lane >> 4;
    const int pid = blockIdx.x;              // 0..15
    const int bh = blockIdx.y;
    const int b = bh >> 4, h = bh & 15;
    const int QT_lo = pid, QT_hi = 31 - pid;

    const size_t base = ((size_t)b * S) * TD + (size_t)h * 64;
    const unsigned short* qp = qkv + base;
    const unsigned short* kp = qkv + base + D;
    const unsigned short* vp = qkv + base + 2 * D;

    // Q fragments straight from global (B-operand layout: n=q=lane&15)
    bf16x8 aq_hi[2], aq_lo[2];
    {
        const unsigned short* gh = qp + (size_t)(QT_hi * 64 + w * 16 + l15) * TD + l4 * 8;
        aq_hi[0] = *reinterpret_cast<const bf16x8*>(gh);
        aq_hi[1] = *reinterpret_cast<const bf16x8*>(gh + 32);
        const unsigned short* gl = qp + (size_t)(QT_lo * 64 + w * 16 + l15) * TD + l4 * 8;
        aq_lo[0] = *reinterpret_cast<const bf16x8*>(gl);
        aq_lo[1] = *reinterpret_cast<const bf16x8*>(gl + 32);
    }

    f32x4 oc_hi[4] = {}, oc_lo[4] = {};      // O^T frags: row=hd, col=q
    float m_hi = -1e30f, l_hi = 0.f, m_lo = -1e30f, l_lo = 0.f;

    const float L2E = 1.44269504f;

    // ---- staging helpers
    auto stageK = [&](int j0, int buf) {
#pragma unroll
        for (int rnd = 0; rnd < 2; ++rnd) {
            int c = rnd * 256 + t;
            int row = c >> 3, hh = c & 7;
            const unsigned short* src = kp + (size_t)(j0 * 64 + row) * TD + ((hh ^ (row & 7)) * 8);
            __builtin_amdgcn_global_load_lds((gv_t*)src, (lv_t*)(Ks[buf] + c * 8), 16, 0, 0);
        }
    };
    const int v_hd = (t & 31) * 2, v_kvb = (t >> 5) * 8;
    unsigned int vv[8];
    auto loadV = [&](int j0) {
        const unsigned short* vsrc = vp + (size_t)(j0 * 64 + v_kvb) * TD + v_hd;
#pragma unroll
        for (int e = 0; e < 8; ++e)
            vv[e] = *reinterpret_cast<const unsigned int*>(vsrc + (size_t)e * TD);
    };
    auto writeV = [&](int buf) {
        unsigned int r0[4], r1[4];
#pragma unroll
        for (int i = 0; i < 4; ++i) {
            r0[i] = __builtin_amdgcn_perm(vv[2 * i + 1], vv[2 * i], 0x05040100u);
            r1[i] = __builtin_amdgcn_perm(vv[2 * i + 1], vv[2 * i], 0x07060302u);
        }
        int g0 = (v_kvb >> 3) ^ (v_hd & 7);
        int g1 = (v_kvb >> 3) ^ ((v_hd + 1) & 7);
        *reinterpret_cast<uint4*>(Vt[buf] + v_hd * 64 + g0 * 8) = make_uint4(r0[0], r0[1], r0[2], r0[3]);
        *reinterpret_cast<uint4*>(Vt[buf] + (v_hd + 1) * 64 + g1 * 8) = make_uint4(r1[0], r1[1], r1[2], r1[3]);
    };

    auto compute = [&](const bf16x8* aq, f32x4* oc, float& mR, float& lR, bool diag, int buf) {
        // ---- S^T = mfma(K, Q): lane holds kv = jn*16 + l4*4 + r for q = w*16+l15
        f32x4 sc[4];
        __builtin_amdgcn_s_setprio(1);
#pragma unroll
        for (int jn = 0; jn < 4; ++jn) {
            f32x4 s = {};
#pragma unroll
            for (int kk = 0; kk < 2; ++kk) {
                int row = jn * 16 + l15;
                int g = (kk * 4 + l4) ^ (l15 & 7);
                bf16x8 ak = *reinterpret_cast<const bf16x8*>(Ks[buf] + row * 64 + g * 8);
                s = __builtin_amdgcn_mfma_f32_16x16x32_bf16(ak, aq[kk], s, 0, 0, 0);
            }
            sc[jn] = s;
        }
        __builtin_amdgcn_s_setprio(0);
        if (diag) {
            int ql = w * 16 + l15;
#pragma unroll
            for (int jn = 0; jn < 4; ++jn)
#pragma unroll
                for (int r = 0; r < 4; ++r)
                    if (jn * 16 + l4 * 4 + r > ql) sc[jn][r] = -1e30f;
        }
        // ---- online softmax (lane-local row)
        float pm = -1e30f;
#pragma unroll
        for (int jn = 0; jn < 4; ++jn) {
            float a = fmaxf(sc[jn][0], sc[jn][1]);
            float c = fmaxf(sc[jn][2], sc[jn][3]);
            pm = fmaxf(pm, fmaxf(a, c));
        }
        pm = fmaxf(pm, __shfl_xor(pm, 16));
        pm = fmaxf(pm, __shfl_xor(pm, 32));
        float mnew = fmaxf(mR, pm);
        float alpha = exp2f((mR - mnew) * L2E);
        float mn2 = mnew * L2E;
        float ps = 0.f;
#pragma unroll
        for (int jn = 0; jn < 4; ++jn) {
            float p0 = exp2f(sc[jn][0] * L2E - mn2);
            float p1 = exp2f(sc[jn][1] * L2E - mn2);
            float p2 = exp2f(sc[jn][2] * L2E - mn2);
            float p3 = exp2f(sc[jn][3] * L2E - mn2);
            sc[jn][0] = p0; sc[jn][1] = p1; sc[jn][2] = p2; sc[jn][3] = p3;
            ps += (p0 + p1) + (p2 + p3);
        }
        ps += __shfl_xor(ps, 16);
        ps += __shfl_xor(ps, 32);
        lR = lR * alpha + ps;
        mR = mnew;
#pragma unroll
        for (int jc = 0; jc < 4; ++jc) oc[jc] *= alpha;
        // ---- P^T -> Ps[w] via cvt_pk + b64 writes (granule-swizzled by q)
        const int q = l15;
#pragma unroll
        for (int jn = 0; jn < 4; ++jn) {
            unsigned int lo = cvt_pk_bf16(sc[jn][0], sc[jn][1]);
            unsigned int hi = cvt_pk_bf16(sc[jn][2], sc[jn][3]);
            int kv0 = jn * 16 + l4 * 4;
            int g = (kv0 >> 3) ^ (q & 7);
            *reinterpret_cast<uint2*>(Ps[w] + q * 64 + g * 8 + (kv0 & 7)) = make_uint2(lo, hi);
        }
        // ---- O^T += mfma(V^T, P)
        __builtin_amdgcn_s_setprio(1);
#pragma unroll
        for (int kk = 0; kk < 2; ++kk) {
            int gq = (kk * 4 + l4) ^ (q & 7);
            bf16x8 bp = *reinterpret_cast<const bf16x8*>(Ps[w] + q * 64 + gq * 8);
#pragma unroll
            for (int jc = 0; jc < 4; ++jc) {
                int hdrow = jc * 16 + l15;
                int gv = (kk * 4 + l4) ^ (l15 & 7);
                bf16x8 av = *reinterpret_cast<const bf16x8*>(Vt[buf] + hdrow * 64 + gv * 8);
                oc[jc] = __builtin_amdgcn_mfma_f32_16x16x32_bf16(av, bp, oc[jc], 0, 0, 0);
            }
        }
        __builtin_amdgcn_s_setprio(0);
    };

    // ---- prologue: stage tile 0 into buf 0
    stageK(0, 0);
    loadV(0);
    writeV(0);
    __syncthreads();

    for (int j0 = 0; j0 <= QT_hi; ++j0) {
        const int cur = j0 & 1, nxt = cur ^ 1;
        const bool have_next = (j0 < QT_hi);
        if (have_next) {          // issue next tile's loads before compute
            stageK(j0 + 1, nxt);
            loadV(j0 + 1);
        }
        compute(aq_hi, oc_hi, m_hi, l_hi, j0 == QT_hi, cur);
        if (j0 <= QT_lo) compute(aq_lo, oc_lo, m_lo, l_lo, j0 == QT_lo, cur);
        if (have_next) writeV(nxt);   // waits vmcnt for vv, then ds_write
        __syncthreads();
    }

    // ---- epilogue: ctx[q][hd] = O^T / l  (cvt_pk + b64 stores)
    auto epi = [&](f32x4* oc, float lR, int QT) {
        float inv = 1.0f / lR;
        size_t qg = (size_t)QT * 64 + w * 16 + l15;
        unsigned short* crow = ctx + ((size_t)b * S + qg) * D + h * 64;
#pragma unroll
        for (int jc = 0; jc < 4; ++jc) {
            unsigned int pk0 = cvt_pk_bf16(oc[jc][0] * inv, oc[jc][1] * inv);
            unsigned int pk1 = cvt_pk_bf16(oc[jc][2] * inv, oc[jc][3] * inv);
            *reinterpret_cast<uint2*>(crow + jc * 16 + l4 * 4) = make_uint2(pk0, pk1);
        }
    };
    epi(oc_hi, l_hi, QT_hi);
    epi(oc_lo, l_lo, QT_lo);
}

// ---------------------------------------------------------------- launch
extern "C" void kernel_launch(void* const* d_in, const int* in_sizes, int n_in,
                              void* d_out, int out_size, void* d_ws, size_t ws_size,
                              hipStream_t stream) {
    const float* x = (const float*)d_in[0];
    const float* Wqkv = (const float*)d_in[1];
    const float* bqkv = (const float*)d_in[2];
    const float* Wout = (const float*)d_in[3];
    float* out = (float*)d_out;

    const int B = 2, S = 2048, D = 1024, TD = 3072;
    const int M = B * S;  // 4096

    char* ws = (char*)d_ws;
    unsigned short* x_bf  = (unsigned short*)(ws);               // 8 MiB
    unsigned short* wqkvT = (unsigned short*)(ws + 8388608);     // 6 MiB  [3072][1024]
    unsigned short* woutT = (unsigned short*)(ws + 14680064);    // 2 MiB  [1024][1024]
    unsigned short* qkv   = (unsigned short*)(ws + 16777216);    // 24 MiB [4096][3072]
    unsigned short* ctx   = (unsigned short*)(ws + 41943040);    // 8 MiB  [4096][1024]

    convert_f32_bf16<<<dim3((M * D / 4 + 255) / 256), dim3(256), 0, stream>>>(x, x_bf, M * D / 4);
    transpose_convert<<<dim3(TD / 32, D / 32), dim3(32, 32), 0, stream>>>(Wqkv, wqkvT, D, TD);
    transpose_convert<<<dim3(D / 32, D / 32), dim3(32, 32), 0, stream>>>(Wout, woutT, D, D);

    gemm_bt<true, true, true><<<dim3(TD / 128, M / 128), dim3(256), 0, stream>>>(
        x_bf, wqkvT, bqkv, (void*)qkv, M, TD, D);

    attn_fwd<<<dim3(16, 32), dim3(256), 0, stream>>>(qkv, ctx, S);

    gemm_bt<false, false, false><<<dim3(D / 128, M / 128), dim3(256), 0, stream>>>(
        ctx, woutT, nullptr, (void*)out, M, D, D);
}